// Round 10
// baseline (4202.150 us; speedup 1.0000x reference)
//
#include <hip/hip_runtime.h>
#include <stdint.h>

// Problem dims
#define T_   512
#define B_   64
#define E_   512
#define H_   1024
#define G4   4096        // 4*H
#define TCH  128         // T chunk for gates buffer
#define MCH  (TCH*B_)    // 8192 rows per chunk
#define BH   (B_*H_)
#define HSTRIDE (BH + 128)   // +256B pad per step region

typedef __attribute__((ext_vector_type(8))) short short8;
typedef __attribute__((ext_vector_type(4))) float f32x4;

__device__ __forceinline__ unsigned short f2bf(float f) {
  unsigned u = __builtin_bit_cast(unsigned, f);
  u += 0x7FFFu + ((u >> 16) & 1u);
  return (unsigned short)(u >> 16);
}
__device__ __forceinline__ float bf2f(unsigned short h) {
  return __builtin_bit_cast(float, ((unsigned)h) << 16);
}
__device__ __forceinline__ float sigm(float x) { return 1.f / (1.f + __expf(-x)); }
__device__ __forceinline__ float tanh_f(float x) {
  x = fmaxf(x, -30.f);
  float e = __expf(-2.f * x);
  return (1.f - e) / (1.f + e);
}

// perm1: n = (kblk16, gate, uu16) -> orig = gate*1024 + (n>>6)*16 + (n&15)
__device__ __forceinline__ int perm1_orig(int n) {
  return ((n >> 4) & 3) * 1024 + (n >> 6) * 16 + (n & 15);
}

// ---------------- prep: weight convert+permute ----------------
__global__ void prep_w_kernel(const float* __restrict__ src, unsigned short* __restrict__ dst,
                              int kshift) {   // K/4 = 1<<kshift; dst pitch = K, perm1 rows
  const int idx = blockIdx.x * 256 + threadIdx.x;
  const int n = idx >> kshift;
  const int k4 = idx & ((1 << kshift) - 1);
  const int K = 4 << kshift;
  const int orig = perm1_orig(n);
  const float4 v = *((const float4*)(src + (size_t)orig * K) + k4);
  uint2 pk;
  pk.x = (unsigned)f2bf(v.x) | ((unsigned)f2bf(v.y) << 16);
  pk.y = (unsigned)f2bf(v.z) | ((unsigned)f2bf(v.w) << 16);
  *((uint2*)(dst + (size_t)n * K) + k4) = pk;
}

// fused L2 weight: dst[4096][2048] perm1 rows; koff=0 <- Wih1, koff=1024 <- Whh1
__global__ void prep_w2_kernel(const float* __restrict__ src, unsigned short* __restrict__ dst,
                               int koff) {
  const int idx = blockIdx.x * 256 + threadIdx.x;  // 4096 blocks
  const int n = idx >> 8;
  const int k4 = idx & 255;        // K/4 = 256
  const int orig = perm1_orig(n);
  const float4 v = *((const float4*)(src + (size_t)orig * 1024) + k4);
  uint2 pk;
  pk.x = (unsigned)f2bf(v.x) | ((unsigned)f2bf(v.y) << 16);
  pk.y = (unsigned)f2bf(v.z) | ((unsigned)f2bf(v.w) << 16);
  *((uint2*)(dst + (size_t)n * 2048 + koff) + k4) = pk;
}

__global__ void prep_bias_kernel(const float* __restrict__ bih0, const float* __restrict__ bhh0,
                                 const float* __restrict__ bih1, const float* __restrict__ bhh1,
                                 float* __restrict__ b0, float* __restrict__ b2) {
  const int n = blockIdx.x * 256 + threadIdx.x;  // 4096
  const int o = perm1_orig(n);
  b0[n] = bih0[o] + bhh0[o];
  b2[n] = bih1[o] + bhh1[o];
}

// ---------------- projection GEMM with fused embedding gather ----------------
__global__ __launch_bounds__(256, 2) void proj_kernel(
    const int* __restrict__ tok, const float* __restrict__ emb,
    const unsigned short* __restrict__ Bw,
    const float* __restrict__ bias, unsigned short* __restrict__ Cout) {
  __shared__ unsigned short lsA[128 * 32];
  __shared__ unsigned short lsB[128 * 32];
  const int tid = threadIdx.x;
  const int row0 = blockIdx.x * 128;
  const int col0 = blockIdx.y * 128;
  const int w = tid >> 6, l = tid & 63, l16 = l & 15, kq = l >> 4;
  const int wr = w >> 1, wc = w & 1;
  const int sr = tid >> 2, sc = (tid & 3) * 8;
  f32x4 acc[4][4];
#pragma unroll
  for (int m = 0; m < 4; ++m)
#pragma unroll
    for (int n = 0; n < 4; ++n) acc[m][n] = (f32x4){0.f, 0.f, 0.f, 0.f};

  const int tr1 = tok[row0 + sr];
  const int tr2 = tok[row0 + 64 + sr];
  const float* Ea = emb + (size_t)tr1 * E_ + sc;
  const float* Eb = emb + (size_t)tr2 * E_ + sc;
  const unsigned short* Bb  = Bw + (size_t)(col0 + sr) * E_ + sc;
  const unsigned short* Bb2 = Bb + (size_t)64 * E_;

  for (int k0 = 0; k0 < E_; k0 += 32) {
    float4 a00 = *(const float4*)(Ea + k0), a01 = *(const float4*)(Ea + k0 + 4);
    float4 a10 = *(const float4*)(Eb + k0), a11 = *(const float4*)(Eb + k0 + 4);
    short8 vb0 = *(const short8*)(Bb + k0);
    short8 vb1 = *(const short8*)(Bb2 + k0);
    __syncthreads();
    short8 pa0, pa1;
    pa0[0]=(short)f2bf(a00.x); pa0[1]=(short)f2bf(a00.y); pa0[2]=(short)f2bf(a00.z); pa0[3]=(short)f2bf(a00.w);
    pa0[4]=(short)f2bf(a01.x); pa0[5]=(short)f2bf(a01.y); pa0[6]=(short)f2bf(a01.z); pa0[7]=(short)f2bf(a01.w);
    pa1[0]=(short)f2bf(a10.x); pa1[1]=(short)f2bf(a10.y); pa1[2]=(short)f2bf(a10.z); pa1[3]=(short)f2bf(a10.w);
    pa1[4]=(short)f2bf(a11.x); pa1[5]=(short)f2bf(a11.y); pa1[6]=(short)f2bf(a11.z); pa1[7]=(short)f2bf(a11.w);
    *(short8*)&lsA[sr * 32 + sc] = pa0;
    *(short8*)&lsA[(64 + sr) * 32 + sc] = pa1;
    *(short8*)&lsB[sr * 32 + sc] = vb0;
    *(short8*)&lsB[(64 + sr) * 32 + sc] = vb1;
    __syncthreads();
    short8 af[4], bfr[4];
#pragma unroll
    for (int m = 0; m < 4; ++m) af[m] = *(const short8*)&lsA[(wr * 64 + m * 16 + l16) * 32 + kq * 8];
#pragma unroll
    for (int n = 0; n < 4; ++n) bfr[n] = *(const short8*)&lsB[(wc * 64 + n * 16 + l16) * 32 + kq * 8];
#pragma unroll
    for (int m = 0; m < 4; ++m)
#pragma unroll
      for (int n = 0; n < 4; ++n)
        acc[m][n] = __builtin_amdgcn_mfma_f32_16x16x32_bf16(af[m], bfr[n], acc[m][n], 0, 0, 0);
  }
#pragma unroll
  for (int n = 0; n < 4; ++n) {
    const int col = col0 + wc * 64 + n * 16 + l16;
    const float bv = bias[col];
#pragma unroll
    for (int m = 0; m < 4; ++m)
#pragma unroll
      for (int r = 0; r < 4; ++r) {
        const int row = row0 + wr * 64 + m * 16 + kq * 4 + r;
        Cout[(size_t)row * G4 + col] = f2bf(acc[m][n][r] + bv);
      }
  }
}

// ---------------- fused persistent recurrent kernel ----------------
// 256 WGs x 512 thr, LDS ~147.5 KB -> 1 WG/CU. Role = bid&7 (XCD affinity under RR dispatch):
//   role 0..3: L1 group g4=role (rows [g4*16,+16)), slot=bid>>3 in 0..31, 128 perm cols,
//              K=1024, 8-wave K-split 128. Whole group on ONE XCD -> h1 ingest L2-shared.
//   role 4..7: L2 group G=(role-4)>>1 (rows [G*32,+32)), slot64=(bid>>3)*2+((role-4)&1),
//              64 perm cols, K=2048 ([h1[t2]; h2[t2-1]]), 8-wave split 256.
// Sync (all r8-proven primitives): agent relaxed atomic h publish (write-through);
// per-wave vmcnt(0) release -> LDS wcnt -> 8th wave publishes single agent flag;
// wave 0 polls flags, broadcasts via LDS `ready`; waves 1-7 spin on LDS.
// Parity-double-buffered LDS exchange, ONE barrier per step.
// flags: [0..127] l1f = g4*32+slot; [128..255] l2f = G*64+slot64.
__global__ __launch_bounds__(512, 1) void fused_kernel(
    const unsigned short* __restrict__ Whh0p,   // [4096][1024] perm1
    const unsigned short* __restrict__ W2p,     // [4096][2048] perm1
    const unsigned short* __restrict__ xw,      // [TCH*64][4096]
    const float* __restrict__ bias2,            // [4096] perm1
    unsigned short* __restrict__ h1buf, unsigned short* __restrict__ h2buf,
    float* __restrict__ c1buf, float* __restrict__ c2buf,
    int t0, int S, unsigned* __restrict__ flags) {
  __shared__ float smem[2][18432];   // 147456 B (L1 uses 16896, L2 uses 18432 floats/parity)
  __shared__ unsigned ready, wcnt;
  const int tid = threadIdx.x, bid = blockIdx.x;
  const int w = tid >> 6, l = tid & 63, l16 = l & 15, kq = l >> 4;
  const int role = bid & 7, blk = bid >> 3;
  if (tid == 0) { ready = 0; wcnt = 0; }
  __syncthreads();
  unsigned* l1f = flags;          // [4][32]
  unsigned* l2f = flags + 128;    // [2][64]
  unsigned pc = 0;

  if (role < 4) {
    // ================= L1: group g4, M=16, cols 128, K=1024 =================
    const int g4 = role, slot = blk;
    const int row = tid >> 5, u = tid & 31;
    const int grow = g4 * 16 + row;
    short8 bfr[8][4];   // 128 VGPR resident weights
#pragma unroll
    for (int n = 0; n < 8; ++n) {
      const unsigned short* bp = Whh0p + (size_t)(slot * 128 + n * 16 + l16) * H_ + w * 128 + kq * 8;
#pragma unroll
      for (int ks = 0; ks < 4; ++ks) bfr[n][ks] = *(const short8*)(bp + ks * 32);
    }
    float c0 = (t0 > 0) ? c1buf[(size_t)grow * H_ + slot * 32 + u] : 0.f;
    unsigned xcur[4];
    {
      const unsigned short* xb = xw + (size_t)grow * G4 + slot * 128 + (u >> 4) * 64 + (u & 14);
#pragma unroll
      for (int gt = 0; gt < 4; ++gt) xcur[gt] = *(const unsigned*)(xb + gt * 16);
    }
    for (int s = 0; s < S; ++s) {
      const int t1 = t0 + s;
      if (t1 >= T_) break;
      const int p = s & 1;
      if (s >= 1) {   // s==0: deps satisfied by previous launch
        const unsigned tok = (unsigned)t1;
        if (w == 0) {
          const unsigned* fp = l1f + g4 * 32 + (l & 31);
          for (;;) {
            unsigned v = __hip_atomic_load(fp, __ATOMIC_RELAXED, __HIP_MEMORY_SCOPE_AGENT);
            if (__all((int)(v >= tok))) break;
            __builtin_amdgcn_s_sleep(1);
          }
          __hip_atomic_store(&ready, tok, __ATOMIC_RELAXED, __HIP_MEMORY_SCOPE_WORKGROUP);
        } else {
          while (__hip_atomic_load(&ready, __ATOMIC_RELAXED, __HIP_MEMORY_SCOPE_WORKGROUP) < tok)
            __builtin_amdgcn_s_sleep(1);
        }
        asm volatile("" ::: "memory");
      }
      f32x4 acc[8];
#pragma unroll
      for (int n = 0; n < 8; ++n) acc[n] = (f32x4){0.f, 0.f, 0.f, 0.f};
      if (t1 > 0) {
        const unsigned short* hp = h1buf + (size_t)(t1 - 1) * HSTRIDE + (size_t)(g4 * 16 + l16) * H_ + w * 128 + kq * 8;
        short8 ah[4];
#pragma unroll
        for (int ks = 0; ks < 4; ++ks) ah[ks] = *(const short8*)(hp + ks * 32);
#pragma unroll
        for (int ks = 0; ks < 4; ++ks)
#pragma unroll
          for (int n = 0; n < 8; ++n)
            acc[n] = __builtin_amdgcn_mfma_f32_16x16x32_bf16(ah[ks], bfr[n][ks], acc[n], 0, 0, 0);
      }
#pragma unroll
      for (int n = 0; n < 8; ++n)
#pragma unroll
        for (int r = 0; r < 4; ++r)
          smem[p][(size_t)(w * 16 + kq * 4 + r) * 132 + n * 16 + l16] = acc[n][r];
      __syncthreads();   // barrier A (only barrier per step; parity dbuf protects reuse)
      float gs[4];
#pragma unroll
      for (int gt = 0; gt < 4; ++gt) {
        const int col = (u >> 4) * 64 + gt * 16 + (u & 15);
        float t = 0.f;
#pragma unroll
        for (int w2 = 0; w2 < 8; ++w2) t += smem[p][(size_t)(w2 * 16 + row) * 132 + col];
        gs[gt] = t + bf2f((unsigned short)((u & 1) ? (xcur[gt] >> 16) : (xcur[gt] & 0xffff)));
      }
      float iv = sigm(gs[0]), fv = sigm(gs[1]), gv = tanh_f(gs[2]), ov = sigm(gs[3]);
      c0 = fv * c0 + iv * gv;
      float hval = ov * tanh_f(c0);
      unsigned my = (unsigned)f2bf(hval);
      unsigned oth = (unsigned)__shfl_xor((int)my, 1);
      if (!(u & 1)) {
        unsigned pk = my | (oth << 16);
        unsigned* dst = (unsigned*)(h1buf + (size_t)t1 * HSTRIDE + (size_t)grow * H_ + slot * 32 + u);
        __hip_atomic_store(dst, pk, __ATOMIC_RELAXED, __HIP_MEMORY_SCOPE_AGENT);
      }
      // per-wave release: drain own h stores, 8th arriving wave publishes WG flag
      asm volatile("s_waitcnt vmcnt(0)" ::: "memory");
      if (l == 0) {
        unsigned old = __hip_atomic_fetch_add(&wcnt, 1u, __ATOMIC_RELAXED, __HIP_MEMORY_SCOPE_WORKGROUP);
        if (old == 8u * pc + 7u)
          __hip_atomic_store(&l1f[g4 * 32 + slot], (unsigned)(t1 + 1),
                             __ATOMIC_RELAXED, __HIP_MEMORY_SCOPE_AGENT);
      }
      if (s + 1 < S && t1 + 1 < T_) {   // xw prefetch flies through next step's wait
        const unsigned short* xb = xw + (size_t)(s + 1) * (B_ * G4) + (size_t)grow * G4
                                 + slot * 128 + (u >> 4) * 64 + (u & 14);
#pragma unroll
        for (int gt = 0; gt < 4; ++gt) xcur[gt] = *(const unsigned*)(xb + gt * 16);
      }
      pc += 1;
    }
    if (t0 < T_) c1buf[(size_t)grow * H_ + slot * 32 + u] = c0;
  } else {
    // ================= L2: group G, M=32, cols 64, K=2048 =================
    const int G = (role - 4) >> 1;
    const int j = blk * 2 + ((role - 4) & 1);   // 0..63
    const int row = tid >> 4, u = tid & 15;
    const int grow = G * 32 + row;
    short8 bf2[4][8];   // 128 VGPR resident weights
#pragma unroll
    for (int st = 0; st < 4; ++st) {
      const unsigned short* bp = W2p + (size_t)(j * 64 + st * 16 + l16) * 2048 + w * 256 + kq * 8;
#pragma unroll
      for (int ks = 0; ks < 8; ++ks) bf2[st][ks] = *(const short8*)(bp + ks * 32);
    }
    float bias_r[4];
#pragma unroll
    for (int gt = 0; gt < 4; ++gt) bias_r[gt] = bias2[j * 64 + gt * 16 + u];
    float c0 = (t0 > 0) ? c2buf[(size_t)grow * H_ + j * 16 + u] : 0.f;
    for (int s = 0; s < S; ++s) {
      const int t2 = t0 + s - 1;
      if (t2 >= T_) break;
      if (t2 < 0) continue;
      const int p = s & 1;
      if (s >= 1) {
        const unsigned tok = (unsigned)(t0 + s);
        const unsigned tgA = (unsigned)(t2 + 1);   // h1 producers (groups 2G,2G+1)
        const unsigned tgB = (unsigned)t2;         // h2 producers
        if (w == 0) {
          const unsigned* fpA = l1f + G * 64 + l;
          const unsigned* fpB = l2f + G * 64 + l;
          for (;;) {
            unsigned v1 = __hip_atomic_load(fpA, __ATOMIC_RELAXED, __HIP_MEMORY_SCOPE_AGENT);
            unsigned v2 = __hip_atomic_load(fpB, __ATOMIC_RELAXED, __HIP_MEMORY_SCOPE_AGENT);
            if (__all((int)((v1 >= tgA) && (v2 >= tgB)))) break;
            __builtin_amdgcn_s_sleep(1);
          }
          __hip_atomic_store(&ready, tok, __ATOMIC_RELAXED, __HIP_MEMORY_SCOPE_WORKGROUP);
        } else {
          while (__hip_atomic_load(&ready, __ATOMIC_RELAXED, __HIP_MEMORY_SCOPE_WORKGROUP) < tok)
            __builtin_amdgcn_s_sleep(1);
        }
        asm volatile("" ::: "memory");
      }
      f32x4 acc[2][4];
#pragma unroll
      for (int rf = 0; rf < 2; ++rf)
#pragma unroll
        for (int st = 0; st < 4; ++st) acc[rf][st] = (f32x4){0.f, 0.f, 0.f, 0.f};
      const bool isH2 = (w >= 4);
      if (!isH2 || t2 > 0) {
        const unsigned short* ap = isH2
            ? (h2buf + (size_t)(t2 - 1) * HSTRIDE + (size_t)(G * 32 + l16) * H_ + (w - 4) * 256 + kq * 8)
            : (h1buf + (size_t)t2 * HSTRIDE + (size_t)(G * 32 + l16) * H_ + w * 256 + kq * 8);
        short8 ah[2][8];
#pragma unroll
        for (int ks = 0; ks < 8; ++ks)
#pragma unroll
          for (int rf = 0; rf < 2; ++rf) ah[rf][ks] = *(const short8*)(ap + rf * 16 * H_ + ks * 32);
#pragma unroll
        for (int ks = 0; ks < 8; ++ks)
#pragma unroll
          for (int st = 0; st < 4; ++st) {
            acc[0][st] = __builtin_amdgcn_mfma_f32_16x16x32_bf16(ah[0][ks], bf2[st][ks], acc[0][st], 0, 0, 0);
            acc[1][st] = __builtin_amdgcn_mfma_f32_16x16x32_bf16(ah[1][ks], bf2[st][ks], acc[1][st], 0, 0, 0);
          }
      }
#pragma unroll
      for (int rf = 0; rf < 2; ++rf)
#pragma unroll
        for (int st = 0; st < 4; ++st)
#pragma unroll
          for (int r = 0; r < 4; ++r)
            smem[p][(size_t)((w * 4 + st) * 32 + rf * 16 + kq * 4 + r) * 18 + l16] = acc[rf][st][r];
      __syncthreads();   // barrier A
      float gs[4];
#pragma unroll
      for (int gt = 0; gt < 4; ++gt) {
        float t = 0.f;
#pragma unroll
        for (int w2 = 0; w2 < 8; ++w2) t += smem[p][(size_t)((w2 * 4 + gt) * 32 + row) * 18 + u];
        gs[gt] = t + bias_r[gt];
      }
      float iv = sigm(gs[0]), fv = sigm(gs[1]), gv = tanh_f(gs[2]), ov = sigm(gs[3]);
      c0 = fv * c0 + iv * gv;
      float hval = ov * tanh_f(c0);
      unsigned my = (unsigned)f2bf(hval);
      unsigned oth = (unsigned)__shfl_xor((int)my, 1);
      if (!(u & 1)) {
        unsigned pk = my | (oth << 16);
        unsigned* dst = (unsigned*)(h2buf + (size_t)t2 * HSTRIDE + (size_t)grow * H_ + j * 16 + u);
        __hip_atomic_store(dst, pk, __ATOMIC_RELAXED, __HIP_MEMORY_SCOPE_AGENT);
      }
      asm volatile("s_waitcnt vmcnt(0)" ::: "memory");
      if (l == 0) {
        unsigned old = __hip_atomic_fetch_add(&wcnt, 1u, __ATOMIC_RELAXED, __HIP_MEMORY_SCOPE_WORKGROUP);
        if (old == 8u * pc + 7u)
          __hip_atomic_store(&l2f[G * 64 + j], (unsigned)(t2 + 1),
                             __ATOMIC_RELAXED, __HIP_MEMORY_SCOPE_AGENT);
      }
      pc += 1;
    }
    if (t0 + S - 2 >= 0) c2buf[(size_t)grow * H_ + j * 16 + u] = c0;
  }
}

// ---------------- head ----------------
__global__ void head_kernel(const unsigned short* __restrict__ hl, const float* __restrict__ Wd,
                            const float* __restrict__ bdp, float* __restrict__ out) {
  __shared__ float p[256];
  const int tid = threadIdx.x, b = tid >> 2, q = tid & 3;
  const unsigned short* hr = hl + (size_t)b * H_ + q * 256;
  const float* wd = Wd + q * 256;
  float s = 0.f;
#pragma unroll 4
  for (int j = 0; j < 256; j += 8) {
    short8 v = *(const short8*)(hr + j);
#pragma unroll
    for (int i = 0; i < 8; ++i) s += bf2f((unsigned short)v[i]) * wd[j + i];
  }
  p[tid] = s;
  __syncthreads();
  if (q == 0) {
    float tot = p[tid] + p[tid + 1] + p[tid + 2] + p[tid + 3] + bdp[0];
    out[b] = 10.f * sigm(tot);
  }
}

// ---------------- host ----------------
extern "C" void kernel_launch(void* const* d_in, const int* in_sizes, int n_in,
                              void* d_out, int out_size, void* d_ws, size_t ws_size,
                              hipStream_t stream) {
  const int*   tokens = (const int*)d_in[0];
  const float* emb  = (const float*)d_in[1];
  const float* Wih0 = (const float*)d_in[2];
  const float* Whh0 = (const float*)d_in[3];
  const float* bih0 = (const float*)d_in[4];
  const float* bhh0 = (const float*)d_in[5];
  const float* Wih1 = (const float*)d_in[6];
  const float* Whh1 = (const float*)d_in[7];
  const float* bih1 = (const float*)d_in[8];
  const float* bhh1 = (const float*)d_in[9];
  const float* Wd   = (const float*)d_in[10];
  const float* bd   = (const float*)d_in[11];
  float* out = (float*)d_out;
  char* ws = (char*)d_ws;

  // ws layout (bytes)
  const size_t O_WIH0 = 0;                            // 4 MiB  [4096][512]
  const size_t O_WHH0 = O_WIH0 + 4194304;             // 8 MiB  [4096][1024]
  const size_t O_W2   = O_WHH0 + 8388608;             // 16 MiB [4096][2048]
  const size_t O_B0   = O_W2   + 16777216;            // 16 KiB
  const size_t O_B2   = O_B0   + 16384;               // 16 KiB
  const size_t O_GATE = O_B2   + 16384;               // 64 MiB
  const size_t O_H1   = O_GATE + 67108864;
  const size_t O_H2   = O_H1   + (size_t)512 * HSTRIDE * 2;
  const size_t O_C1   = O_H2   + (size_t)512 * HSTRIDE * 2;  // 256 KiB
  const size_t O_C2   = O_C1   + 262144;              // 256 KiB
  const size_t O_FLG  = O_C2   + 262144;              // flags[256] = 1 KiB

  unsigned short* wih0p = (unsigned short*)(ws + O_WIH0);
  unsigned short* whh0p = (unsigned short*)(ws + O_WHH0);
  unsigned short* w2p   = (unsigned short*)(ws + O_W2);
  float* bias0 = (float*)(ws + O_B0);
  float* bias2 = (float*)(ws + O_B2);
  unsigned short* gates = (unsigned short*)(ws + O_GATE);
  unsigned short* h1    = (unsigned short*)(ws + O_H1);
  unsigned short* h2    = (unsigned short*)(ws + O_H2);
  float* c1buf = (float*)(ws + O_C1);
  float* c2buf = (float*)(ws + O_C2);
  unsigned* flags = (unsigned*)(ws + O_FLG);

  hipMemsetAsync(ws + O_FLG, 0, 4096, stream);

  prep_w_kernel<<<2048, 256, 0, stream>>>(Wih0, wih0p, 7);    // K=512, perm1
  prep_w_kernel<<<4096, 256, 0, stream>>>(Whh0, whh0p, 8);    // K=1024, perm1
  prep_w2_kernel<<<4096, 256, 0, stream>>>(Wih1, w2p, 0);     // perm1
  prep_w2_kernel<<<4096, 256, 0, stream>>>(Whh1, w2p, 1024);  // perm1
  prep_bias_kernel<<<16, 256, 0, stream>>>(bih0, bhh0, bih1, bhh1, bias0, bias2);

  for (int c = 0; c < 4; ++c) {
    proj_kernel<<<dim3(64, 32), 256, 0, stream>>>(tokens + (size_t)c * MCH, emb, wih0p, bias0, gates);
    // last chunk runs one extra macro-step so L2 finishes t=511 (no drain launch)
    const int S = (c == 3) ? (TCH + 1) : TCH;
    fused_kernel<<<256, 512, 0, stream>>>(whh0p, w2p, gates, bias2, h1, h2, c1buf, c2buf,
                                          c * TCH, S, flags);
  }
  head_kernel<<<1, 256, 0, stream>>>(h2 + (size_t)511 * HSTRIDE, Wd, bd, out);

  (void)in_sizes; (void)n_in; (void)out_size; (void)ws_size;
}

// Round 11
// 3357.668 us; speedup vs baseline: 1.2515x; 1.2515x over previous
//
#include <hip/hip_runtime.h>
#include <stdint.h>

// Problem dims
#define T_   512
#define B_   64
#define E_   512
#define H_   1024
#define G4   4096        // 4*H
#define TCH  128         // T chunk for gates buffer
#define MCH  (TCH*B_)    // 8192 rows per chunk
#define BH   (B_*H_)
#define HSTRIDE (BH + 128)   // +256B pad per step region

typedef __attribute__((ext_vector_type(8))) short short8;
typedef __attribute__((ext_vector_type(4))) float f32x4;

__device__ __forceinline__ unsigned short f2bf(float f) {
  unsigned u = __builtin_bit_cast(unsigned, f);
  u += 0x7FFFu + ((u >> 16) & 1u);
  return (unsigned short)(u >> 16);
}
__device__ __forceinline__ float bf2f(unsigned short h) {
  return __builtin_bit_cast(float, ((unsigned)h) << 16);
}
__device__ __forceinline__ float sigm(float x) { return 1.f / (1.f + __expf(-x)); }
__device__ __forceinline__ float tanh_f(float x) {
  x = fmaxf(x, -30.f);
  float e = __expf(-2.f * x);
  return (1.f - e) / (1.f + e);
}

// perm1: n = (kblk16, gate, uu16) -> orig = gate*1024 + (n>>6)*16 + (n&15)
__device__ __forceinline__ int perm1_orig(int n) {
  return ((n >> 4) & 3) * 1024 + (n >> 6) * 16 + (n & 15);
}

// ---------------- prep: weight convert+permute ----------------
__global__ void prep_w_kernel(const float* __restrict__ src, unsigned short* __restrict__ dst,
                              int kshift) {   // K/4 = 1<<kshift; dst pitch = K, perm1 rows
  const int idx = blockIdx.x * 256 + threadIdx.x;
  const int n = idx >> kshift;
  const int k4 = idx & ((1 << kshift) - 1);
  const int K = 4 << kshift;
  const int orig = perm1_orig(n);
  const float4 v = *((const float4*)(src + (size_t)orig * K) + k4);
  uint2 pk;
  pk.x = (unsigned)f2bf(v.x) | ((unsigned)f2bf(v.y) << 16);
  pk.y = (unsigned)f2bf(v.z) | ((unsigned)f2bf(v.w) << 16);
  *((uint2*)(dst + (size_t)n * K) + k4) = pk;
}

// fused L2 weight: dst[4096][2048] perm1 rows; koff=0 <- Wih1, koff=1024 <- Whh1
__global__ void prep_w2_kernel(const float* __restrict__ src, unsigned short* __restrict__ dst,
                               int koff) {
  const int idx = blockIdx.x * 256 + threadIdx.x;  // 4096 blocks
  const int n = idx >> 8;
  const int k4 = idx & 255;        // K/4 = 256
  const int orig = perm1_orig(n);
  const float4 v = *((const float4*)(src + (size_t)orig * 1024) + k4);
  uint2 pk;
  pk.x = (unsigned)f2bf(v.x) | ((unsigned)f2bf(v.y) << 16);
  pk.y = (unsigned)f2bf(v.z) | ((unsigned)f2bf(v.w) << 16);
  *((uint2*)(dst + (size_t)n * 2048 + koff) + k4) = pk;
}

__global__ void prep_bias_kernel(const float* __restrict__ bih0, const float* __restrict__ bhh0,
                                 const float* __restrict__ bih1, const float* __restrict__ bhh1,
                                 float* __restrict__ b0, float* __restrict__ b2) {
  const int n = blockIdx.x * 256 + threadIdx.x;  // 4096
  const int o = perm1_orig(n);
  b0[n] = bih0[o] + bhh0[o];
  b2[n] = bih1[o] + bhh1[o];
}

// ---------------- projection GEMM with fused embedding gather ----------------
__global__ __launch_bounds__(256, 2) void proj_kernel(
    const int* __restrict__ tok, const float* __restrict__ emb,
    const unsigned short* __restrict__ Bw,
    const float* __restrict__ bias, unsigned short* __restrict__ Cout) {
  __shared__ unsigned short lsA[128 * 32];
  __shared__ unsigned short lsB[128 * 32];
  const int tid = threadIdx.x;
  const int row0 = blockIdx.x * 128;
  const int col0 = blockIdx.y * 128;
  const int w = tid >> 6, l = tid & 63, l16 = l & 15, kq = l >> 4;
  const int wr = w >> 1, wc = w & 1;
  const int sr = tid >> 2, sc = (tid & 3) * 8;
  f32x4 acc[4][4];
#pragma unroll
  for (int m = 0; m < 4; ++m)
#pragma unroll
    for (int n = 0; n < 4; ++n) acc[m][n] = (f32x4){0.f, 0.f, 0.f, 0.f};

  const int tr1 = tok[row0 + sr];
  const int tr2 = tok[row0 + 64 + sr];
  const float* Ea = emb + (size_t)tr1 * E_ + sc;
  const float* Eb = emb + (size_t)tr2 * E_ + sc;
  const unsigned short* Bb  = Bw + (size_t)(col0 + sr) * E_ + sc;
  const unsigned short* Bb2 = Bb + (size_t)64 * E_;

  for (int k0 = 0; k0 < E_; k0 += 32) {
    float4 a00 = *(const float4*)(Ea + k0), a01 = *(const float4*)(Ea + k0 + 4);
    float4 a10 = *(const float4*)(Eb + k0), a11 = *(const float4*)(Eb + k0 + 4);
    short8 vb0 = *(const short8*)(Bb + k0);
    short8 vb1 = *(const short8*)(Bb2 + k0);
    __syncthreads();
    short8 pa0, pa1;
    pa0[0]=(short)f2bf(a00.x); pa0[1]=(short)f2bf(a00.y); pa0[2]=(short)f2bf(a00.z); pa0[3]=(short)f2bf(a00.w);
    pa0[4]=(short)f2bf(a01.x); pa0[5]=(short)f2bf(a01.y); pa0[6]=(short)f2bf(a01.z); pa0[7]=(short)f2bf(a01.w);
    pa1[0]=(short)f2bf(a10.x); pa1[1]=(short)f2bf(a10.y); pa1[2]=(short)f2bf(a10.z); pa1[3]=(short)f2bf(a10.w);
    pa1[4]=(short)f2bf(a11.x); pa1[5]=(short)f2bf(a11.y); pa1[6]=(short)f2bf(a11.z); pa1[7]=(short)f2bf(a11.w);
    *(short8*)&lsA[sr * 32 + sc] = pa0;
    *(short8*)&lsA[(64 + sr) * 32 + sc] = pa1;
    *(short8*)&lsB[sr * 32 + sc] = vb0;
    *(short8*)&lsB[(64 + sr) * 32 + sc] = vb1;
    __syncthreads();
    short8 af[4], bfr[4];
#pragma unroll
    for (int m = 0; m < 4; ++m) af[m] = *(const short8*)&lsA[(wr * 64 + m * 16 + l16) * 32 + kq * 8];
#pragma unroll
    for (int n = 0; n < 4; ++n) bfr[n] = *(const short8*)&lsB[(wc * 64 + n * 16 + l16) * 32 + kq * 8];
#pragma unroll
    for (int m = 0; m < 4; ++m)
#pragma unroll
      for (int n = 0; n < 4; ++n)
        acc[m][n] = __builtin_amdgcn_mfma_f32_16x16x32_bf16(af[m], bfr[n], acc[m][n], 0, 0, 0);
  }
#pragma unroll
  for (int n = 0; n < 4; ++n) {
    const int col = col0 + wc * 64 + n * 16 + l16;
    const float bv = bias[col];
#pragma unroll
    for (int m = 0; m < 4; ++m)
#pragma unroll
      for (int r = 0; r < 4; ++r) {
        const int row = row0 + wr * 64 + m * 16 + kq * 4 + r;
        Cout[(size_t)row * G4 + col] = f2bf(acc[m][n][r] + bv);
      }
  }
}

// ---------------- fused persistent recurrent kernel ----------------
// 256 WGs x 512 thr, LDS 86016B -> 1 WG/CU. Role = bid&7 (XCD affinity under RR dispatch):
//   role 0..3: L1 group g4=role (rows [g4*16,+16)), slot=bid>>3 in 0..31, 128 perm cols
//              (32 units x 4 gates), K=1024, 8-wave K-split 128. Group is XCD-pure ->
//              h1 lines IC-fetched once, L2-shared by the other 31 consumer WGs.
//   role 4..7: L2 group G=(role-4)>>1 (rows [G*32,+32)), j=(bid>>3)*2+((role-4)&1) in 0..63,
//              64 perm cols, K=2048 ([h1[t2]; h2[t2-1]]), waves 0-3 h1-half, 4-7 h2-half.
// Sync per step (r8-proven skeleton): wave0 polls producer flags (agent relaxed) ->
// LDS `ready` broadcast; barrier A for split-K exchange; elementwise; agent relaxed
// write-through h publish; barrier B (drains publishes); tid0 single flag store;
// xw prefetch last. Flags monotonic step tokens.
// flags: [0..127] l1f = g4*32+slot; [128..255] l2f = G*64+j.
__global__ __launch_bounds__(512, 1) void fused_kernel(
    const unsigned short* __restrict__ Whh0p,   // [4096][1024] perm1
    const unsigned short* __restrict__ W2p,     // [4096][2048] perm1
    const unsigned short* __restrict__ xw,      // [TCH*64][4096]
    const float* __restrict__ bias2,            // [4096] perm1
    unsigned short* __restrict__ h1buf, unsigned short* __restrict__ h2buf,
    float* __restrict__ c1buf, float* __restrict__ c2buf,
    int t0, int S, unsigned* __restrict__ flags) {
  __shared__ float smem[21504];   // 86016 B (L1 uses 16896 floats, L2 uses 18432)
  __shared__ unsigned ready;
  const int tid = threadIdx.x, bid = blockIdx.x;
  const int w = tid >> 6, l = tid & 63, l16 = l & 15, kq = l >> 4;
  const int role = bid & 7, blk = bid >> 3;
  if (tid == 0) ready = 0;
  __syncthreads();
  unsigned* l1f = flags;          // [4][32]
  unsigned* l2f = flags + 128;    // [2][64]

  if (role < 4) {
    // ================= L1: group g4, M=16, cols 128, K=1024 =================
    const int g4 = role, slot = blk;
    const int row = tid >> 5, u = tid & 31;
    const int grow = g4 * 16 + row;
    short8 bfr[8][4];   // 128 VGPR resident weights
#pragma unroll
    for (int n = 0; n < 8; ++n) {
      const unsigned short* bp = Whh0p + (size_t)(slot * 128 + n * 16 + l16) * H_ + w * 128 + kq * 8;
#pragma unroll
      for (int ks = 0; ks < 4; ++ks) bfr[n][ks] = *(const short8*)(bp + ks * 32);
    }
    float c0 = (t0 > 0) ? c1buf[(size_t)grow * H_ + slot * 32 + u] : 0.f;
    unsigned xcur[4];
    {
      const unsigned short* xb = xw + (size_t)grow * G4 + slot * 128 + (u >> 4) * 64 + (u & 14);
#pragma unroll
      for (int gt = 0; gt < 4; ++gt) xcur[gt] = *(const unsigned*)(xb + gt * 16);
    }
    for (int s = 0; s < S; ++s) {
      const int t1 = t0 + s;
      if (t1 >= T_) break;
      if (s >= 1) {   // s==0: deps satisfied by previous launch
        const unsigned tok = (unsigned)t1;
        if (w == 0) {
          const unsigned* fp = l1f + g4 * 32 + (l & 31);
          for (;;) {
            unsigned v = __hip_atomic_load(fp, __ATOMIC_RELAXED, __HIP_MEMORY_SCOPE_AGENT);
            if (__all((int)(v >= tok))) break;
            __builtin_amdgcn_s_sleep(1);
          }
          __hip_atomic_store(&ready, tok, __ATOMIC_RELAXED, __HIP_MEMORY_SCOPE_WORKGROUP);
        } else {
          while (__hip_atomic_load(&ready, __ATOMIC_RELAXED, __HIP_MEMORY_SCOPE_WORKGROUP) < tok)
            __builtin_amdgcn_s_sleep(1);
        }
        asm volatile("" ::: "memory");
      }
      f32x4 acc[8];
#pragma unroll
      for (int n = 0; n < 8; ++n) acc[n] = (f32x4){0.f, 0.f, 0.f, 0.f};
      if (t1 > 0) {
        const unsigned short* hp = h1buf + (size_t)(t1 - 1) * HSTRIDE + (size_t)(g4 * 16 + l16) * H_ + w * 128 + kq * 8;
        short8 ah[4];
#pragma unroll
        for (int ks = 0; ks < 4; ++ks) ah[ks] = *(const short8*)(hp + ks * 32);
#pragma unroll
        for (int ks = 0; ks < 4; ++ks)
#pragma unroll
          for (int n = 0; n < 8; ++n)
            acc[n] = __builtin_amdgcn_mfma_f32_16x16x32_bf16(ah[ks], bfr[n][ks], acc[n], 0, 0, 0);
      }
#pragma unroll
      for (int n = 0; n < 8; ++n)
#pragma unroll
        for (int r = 0; r < 4; ++r)
          smem[(size_t)(w * 16 + kq * 4 + r) * 132 + n * 16 + l16] = acc[n][r];
      __syncthreads();   // barrier A: split-K partials ready
      float gs[4];
#pragma unroll
      for (int gt = 0; gt < 4; ++gt) {
        const int col = (u >> 4) * 64 + gt * 16 + (u & 15);
        float t = 0.f;
#pragma unroll
        for (int w2 = 0; w2 < 8; ++w2) t += smem[(size_t)(w2 * 16 + row) * 132 + col];
        gs[gt] = t + bf2f((unsigned short)((u & 1) ? (xcur[gt] >> 16) : (xcur[gt] & 0xffff)));
      }
      float iv = sigm(gs[0]), fv = sigm(gs[1]), gv = tanh_f(gs[2]), ov = sigm(gs[3]);
      c0 = fv * c0 + iv * gv;
      float hval = ov * tanh_f(c0);
      unsigned my = (unsigned)f2bf(hval);
      unsigned oth = (unsigned)__shfl_xor((int)my, 1);
      if (!(u & 1)) {
        unsigned pk = my | (oth << 16);
        unsigned* dst = (unsigned*)(h1buf + (size_t)t1 * HSTRIDE + (size_t)grow * H_ + slot * 32 + u);
        __hip_atomic_store(dst, pk, __ATOMIC_RELAXED, __HIP_MEMORY_SCOPE_AGENT);
      }
      __syncthreads();   // barrier B: drains h publishes (per-wave vmcnt 0) + smem reuse
      if (tid == 0)
        __hip_atomic_store(&l1f[g4 * 32 + slot], (unsigned)(t1 + 1),
                           __ATOMIC_RELAXED, __HIP_MEMORY_SCOPE_AGENT);
      if (s + 1 < S && t1 + 1 < T_) {   // xw prefetch flies through next step's wait
        const unsigned short* xb = xw + (size_t)(s + 1) * (B_ * G4) + (size_t)grow * G4
                                 + slot * 128 + (u >> 4) * 64 + (u & 14);
#pragma unroll
        for (int gt = 0; gt < 4; ++gt) xcur[gt] = *(const unsigned*)(xb + gt * 16);
      }
    }
    if (t0 < T_) c1buf[(size_t)grow * H_ + slot * 32 + u] = c0;
  } else {
    // ================= L2: group G, M=32, cols 64, K=2048 =================
    const int G = (role - 4) >> 1;
    const int j = blk * 2 + ((role - 4) & 1);   // 0..63
    const int row = tid >> 4, u = tid & 15;
    const int grow = G * 32 + row;
    short8 bf2[4][8];   // 128 VGPR resident weights
#pragma unroll
    for (int st = 0; st < 4; ++st) {
      const unsigned short* bp = W2p + (size_t)(j * 64 + st * 16 + l16) * 2048 + w * 256 + kq * 8;
#pragma unroll
      for (int ks = 0; ks < 8; ++ks) bf2[st][ks] = *(const short8*)(bp + ks * 32);
    }
    float bias_r[4];
#pragma unroll
    for (int gt = 0; gt < 4; ++gt) bias_r[gt] = bias2[j * 64 + gt * 16 + u];
    float c0 = (t0 > 0) ? c2buf[(size_t)grow * H_ + j * 16 + u] : 0.f;
    for (int s = 0; s < S; ++s) {
      const int t2 = t0 + s - 1;
      if (t2 >= T_) break;
      if (t2 < 0) continue;
      if (s >= 1) {
        const unsigned tok = (unsigned)(t0 + s);
        const unsigned tgA = (unsigned)(t2 + 1);   // h1 producers (groups 2G,2G+1)
        const unsigned tgB = (unsigned)t2;         // h2 producers (0 -> trivially true)
        if (w == 0) {
          const unsigned* fpA = l1f + G * 64 + l;
          const unsigned* fpB = l2f + G * 64 + l;
          for (;;) {
            unsigned v1 = __hip_atomic_load(fpA, __ATOMIC_RELAXED, __HIP_MEMORY_SCOPE_AGENT);
            unsigned v2 = __hip_atomic_load(fpB, __ATOMIC_RELAXED, __HIP_MEMORY_SCOPE_AGENT);
            if (__all((int)((v1 >= tgA) && (v2 >= tgB)))) break;
            __builtin_amdgcn_s_sleep(1);
          }
          __hip_atomic_store(&ready, tok, __ATOMIC_RELAXED, __HIP_MEMORY_SCOPE_WORKGROUP);
        } else {
          while (__hip_atomic_load(&ready, __ATOMIC_RELAXED, __HIP_MEMORY_SCOPE_WORKGROUP) < tok)
            __builtin_amdgcn_s_sleep(1);
        }
        asm volatile("" ::: "memory");
      }
      f32x4 acc[2][4];
#pragma unroll
      for (int rf = 0; rf < 2; ++rf)
#pragma unroll
        for (int st = 0; st < 4; ++st) acc[rf][st] = (f32x4){0.f, 0.f, 0.f, 0.f};
      const bool isH2 = (w >= 4);
      if (!isH2 || t2 > 0) {
        const unsigned short* ap = isH2
            ? (h2buf + (size_t)(t2 - 1) * HSTRIDE + (size_t)(G * 32 + l16) * H_ + (w - 4) * 256 + kq * 8)
            : (h1buf + (size_t)t2 * HSTRIDE + (size_t)(G * 32 + l16) * H_ + w * 256 + kq * 8);
        short8 ah[2][8];
#pragma unroll
        for (int ks = 0; ks < 8; ++ks)
#pragma unroll
          for (int rf = 0; rf < 2; ++rf) ah[rf][ks] = *(const short8*)(ap + rf * 16 * H_ + ks * 32);
#pragma unroll
        for (int ks = 0; ks < 8; ++ks)
#pragma unroll
          for (int st = 0; st < 4; ++st) {
            acc[0][st] = __builtin_amdgcn_mfma_f32_16x16x32_bf16(ah[0][ks], bf2[st][ks], acc[0][st], 0, 0, 0);
            acc[1][st] = __builtin_amdgcn_mfma_f32_16x16x32_bf16(ah[1][ks], bf2[st][ks], acc[1][st], 0, 0, 0);
          }
      }
#pragma unroll
      for (int rf = 0; rf < 2; ++rf)
#pragma unroll
        for (int st = 0; st < 4; ++st)
#pragma unroll
          for (int r = 0; r < 4; ++r)
            smem[(size_t)((w * 4 + st) * 32 + rf * 16 + kq * 4 + r) * 18 + l16] = acc[rf][st][r];
      __syncthreads();   // barrier A
      float gs[4];
#pragma unroll
      for (int gt = 0; gt < 4; ++gt) {
        float t = 0.f;
#pragma unroll
        for (int w2 = 0; w2 < 8; ++w2) t += smem[(size_t)((w2 * 4 + gt) * 32 + row) * 18 + u];
        gs[gt] = t + bias_r[gt];
      }
      float iv = sigm(gs[0]), fv = sigm(gs[1]), gv = tanh_f(gs[2]), ov = sigm(gs[3]);
      c0 = fv * c0 + iv * gv;
      float hval = ov * tanh_f(c0);
      unsigned my = (unsigned)f2bf(hval);
      unsigned oth = (unsigned)__shfl_xor((int)my, 1);
      if (!(u & 1)) {
        unsigned pk = my | (oth << 16);
        unsigned* dst = (unsigned*)(h2buf + (size_t)t2 * HSTRIDE + (size_t)grow * H_ + j * 16 + u);
        __hip_atomic_store(dst, pk, __ATOMIC_RELAXED, __HIP_MEMORY_SCOPE_AGENT);
      }
      __syncthreads();   // barrier B: drains h2 publishes
      if (tid == 0)
        __hip_atomic_store(&l2f[G * 64 + j], (unsigned)(t2 + 1),
                           __ATOMIC_RELAXED, __HIP_MEMORY_SCOPE_AGENT);
    }
    if (t0 + S - 2 >= 0) c2buf[(size_t)grow * H_ + j * 16 + u] = c0;
  }
}

// ---------------- head ----------------
__global__ void head_kernel(const unsigned short* __restrict__ hl, const float* __restrict__ Wd,
                            const float* __restrict__ bdp, float* __restrict__ out) {
  __shared__ float p[256];
  const int tid = threadIdx.x, b = tid >> 2, q = tid & 3;
  const unsigned short* hr = hl + (size_t)b * H_ + q * 256;
  const float* wd = Wd + q * 256;
  float s = 0.f;
#pragma unroll 4
  for (int j = 0; j < 256; j += 8) {
    short8 v = *(const short8*)(hr + j);
#pragma unroll
    for (int i = 0; i < 8; ++i) s += bf2f((unsigned short)v[i]) * wd[j + i];
  }
  p[tid] = s;
  __syncthreads();
  if (q == 0) {
    float tot = p[tid] + p[tid + 1] + p[tid + 2] + p[tid + 3] + bdp[0];
    out[b] = 10.f * sigm(tot);
  }
}

// ---------------- host ----------------
extern "C" void kernel_launch(void* const* d_in, const int* in_sizes, int n_in,
                              void* d_out, int out_size, void* d_ws, size_t ws_size,
                              hipStream_t stream) {
  const int*   tokens = (const int*)d_in[0];
  const float* emb  = (const float*)d_in[1];
  const float* Wih0 = (const float*)d_in[2];
  const float* Whh0 = (const float*)d_in[3];
  const float* bih0 = (const float*)d_in[4];
  const float* bhh0 = (const float*)d_in[5];
  const float* Wih1 = (const float*)d_in[6];
  const float* Whh1 = (const float*)d_in[7];
  const float* bih1 = (const float*)d_in[8];
  const float* bhh1 = (const float*)d_in[9];
  const float* Wd   = (const float*)d_in[10];
  const float* bd   = (const float*)d_in[11];
  float* out = (float*)d_out;
  char* ws = (char*)d_ws;

  // ws layout (bytes)
  const size_t O_WIH0 = 0;                            // 4 MiB  [4096][512]
  const size_t O_WHH0 = O_WIH0 + 4194304;             // 8 MiB  [4096][1024]
  const size_t O_W2   = O_WHH0 + 8388608;             // 16 MiB [4096][2048]
  const size_t O_B0   = O_W2   + 16777216;            // 16 KiB
  const size_t O_B2   = O_B0   + 16384;               // 16 KiB
  const size_t O_GATE = O_B2   + 16384;               // 64 MiB
  const size_t O_H1   = O_GATE + 67108864;
  const size_t O_H2   = O_H1   + (size_t)512 * HSTRIDE * 2;
  const size_t O_C1   = O_H2   + (size_t)512 * HSTRIDE * 2;  // 256 KiB
  const size_t O_C2   = O_C1   + 262144;              // 256 KiB
  const size_t O_FLG  = O_C2   + 262144;              // flags[256] = 1 KiB

  unsigned short* wih0p = (unsigned short*)(ws + O_WIH0);
  unsigned short* whh0p = (unsigned short*)(ws + O_WHH0);
  unsigned short* w2p   = (unsigned short*)(ws + O_W2);
  float* bias0 = (float*)(ws + O_B0);
  float* bias2 = (float*)(ws + O_B2);
  unsigned short* gates = (unsigned short*)(ws + O_GATE);
  unsigned short* h1    = (unsigned short*)(ws + O_H1);
  unsigned short* h2    = (unsigned short*)(ws + O_H2);
  float* c1buf = (float*)(ws + O_C1);
  float* c2buf = (float*)(ws + O_C2);
  unsigned* flags = (unsigned*)(ws + O_FLG);

  hipMemsetAsync(ws + O_FLG, 0, 4096, stream);

  prep_w_kernel<<<2048, 256, 0, stream>>>(Wih0, wih0p, 7);    // K=512, perm1
  prep_w_kernel<<<4096, 256, 0, stream>>>(Whh0, whh0p, 8);    // K=1024, perm1
  prep_w2_kernel<<<4096, 256, 0, stream>>>(Wih1, w2p, 0);     // perm1
  prep_w2_kernel<<<4096, 256, 0, stream>>>(Whh1, w2p, 1024);  // perm1
  prep_bias_kernel<<<16, 256, 0, stream>>>(bih0, bhh0, bih1, bhh1, bias0, bias2);

  for (int c = 0; c < 4; ++c) {
    proj_kernel<<<dim3(64, 32), 256, 0, stream>>>(tokens + (size_t)c * MCH, emb, wih0p, bias0, gates);
    // last chunk runs one extra macro-step so L2 finishes t=511 (no drain launch)
    const int S = (c == 3) ? (TCH + 1) : TCH;
    fused_kernel<<<256, 512, 0, stream>>>(whh0p, w2p, gates, bias2, h1, h2, c1buf, c2buf,
                                          c * TCH, S, flags);
  }
  head_kernel<<<1, 256, 0, stream>>>(h2 + (size_t)511 * HSTRIDE, Wd, bd, out);

  (void)in_sizes; (void)n_in; (void)out_size; (void)ws_size;
}